// Round 2
// baseline (42394.125 us; speedup 1.0000x reference)
//
#include <hip/hip_runtime.h>

// PolicyAwareLSTM: 2-layer LSTM (4096 x 336, 32->64->32) + seq1-MHA (two 32x32
// matmuls; Wq/Wk dead since softmax over len-1 axis == 1) + dense 32->64->24.
// fp32 (no fp32 MFMA on CDNA4) -> VALU + LDS-broadcast design.
//
// Round-2 design: wave-specialized roles, C=2 columns/thread, layer-2 skewed one
// step behind layer-1 (2 barriers/step). Weights pinned in VGPRs via a shared
// wr[192] array + memory-clobber asm (prevents remat into the loop; round-1
// showed VGPR=108 => weights were NOT resident).

#define B_TOTAL 4096
#define T_STEPS 336
#define NT      256
#define RROWS   8

__device__ __forceinline__ float fast_sigmoid(float x) {
    return __fdividef(1.0f, 1.0f + __expf(-x));
}
__device__ __forceinline__ float fast_tanh(float x) {
    float ax = fabsf(x);
    float e  = __expf(-2.0f * ax);
    float r  = __fdividef(1.0f - e, 1.0f + e);
    return __builtin_copysignf(r, x);
}

#define FMA4(acc, hv, base) \
    acc = fmaf(hv.x, wr[(base) + 0], acc); \
    acc = fmaf(hv.y, wr[(base) + 1], acc); \
    acc = fmaf(hv.z, wr[(base) + 2], acc); \
    acc = fmaf(hv.w, wr[(base) + 3], acc);

#define GATE1E(E) { \
    float ig = fast_sigmoid(zi.E), fg = fast_sigmoid(zf.E); \
    float gg = fast_tanh(zg.E),    og = fast_sigmoid(zo.E); \
    c1.E = fmaf(fg, c1.E, ig * gg); h.E = og * fast_tanh(c1.E); }

#define GATE2E(E) { \
    float ig = fast_sigmoid(zi.E), fg = fast_sigmoid(zf.E); \
    float gg = fast_tanh(zg.E),    og = fast_sigmoid(zo.E); \
    c2.E = fmaf(fg, c2.E, ig * gg); h.E = og * fast_tanh(c2.E); }

__global__ __launch_bounds__(NT, 2) void lstm_fused(
    const float* __restrict__ x,
    const float* __restrict__ W1, const float* __restrict__ U1, const float* __restrict__ b1,
    const float* __restrict__ W2, const float* __restrict__ U2, const float* __restrict__ b2,
    const float* __restrict__ Wv, const float* __restrict__ bv,
    const float* __restrict__ Wo, const float* __restrict__ bo,
    const float* __restrict__ Wd1, const float* __restrict__ bd1,
    const float* __restrict__ Wd2, const float* __restrict__ bd2,
    float* __restrict__ out)
{
    __shared__ __align__(16) float4 x_sh[2][RROWS][8];   // x slice, double-buffered
    __shared__ __align__(16) float4 h1_sh[RROWS][16];    // h1: 64 floats/row
    __shared__ __align__(16) float4 h2_sh[RROWS][8];     // h2: 32 floats/row
    __shared__ __align__(16) float  zp1h[RROWS][256];    // z1 partial: h1@U1
    __shared__ __align__(16) float  zp1x[RROWS][256];    // z1 partial: x@W1 + b1
    __shared__ __align__(16) float  z2s [RROWS][128];    // z2 full
    __shared__ float t0_sh[RROWS][32];
    __shared__ float d1_sh[RROWS][64];

    const int tid = threadIdx.x;
    const int l   = tid & 63;
    const int wid = tid >> 6;
    const int r0  = blockIdx.x * RROWS;
    // parity swap (0<->2, 1<->3) so heavy z2 wave pairs with a light wave per SIMD
    const int role = wid ^ (((blockIdx.x >> 8) & 1) << 1);

    // ---- weights in registers; shared array across roles to cap union liveness
    float wr[192];
    float4 bias = make_float4(0.f, 0.f, 0.f, 0.f);

    if (role <= 1) {
        // z1, h1@U1 part: cols {cA, cA+128}, K=64 -> 128 regs
        const int cA = (role == 0) ? l : (64 + l);
        const int cB = cA + 128;
        #pragma unroll
        for (int k = 0; k < 64; ++k) {
            wr[k]      = U1[k * 256 + cA];
            wr[64 + k] = U1[k * 256 + cB];
        }
    } else if (role == 2) {
        // z2 full: cols {l, 64+l}, K=96 -> 192 regs
        const int cA = l, cB = 64 + l;
        #pragma unroll
        for (int k = 0; k < 64; ++k) {
            wr[k]      = W2[k * 128 + cA];
            wr[96 + k] = W2[k * 128 + cB];
        }
        #pragma unroll
        for (int k = 0; k < 32; ++k) {
            wr[64 + k]  = U2[k * 128 + cA];
            wr[160 + k] = U2[k * 128 + cB];
        }
        bias.x = b2[cA]; bias.y = b2[cB];
    } else {
        // z1, x@W1 part: cols {l, 64+l, 128+l, 192+l}, K=32 -> 128 regs
        #pragma unroll
        for (int g = 0; g < 4; ++g) {
            #pragma unroll
            for (int k = 0; k < 32; ++k)
                wr[g * 32 + k] = W1[k * 256 + (g * 64 + l)];
        }
        bias.x = b1[l]; bias.y = b1[64 + l]; bias.z = b1[128 + l]; bias.w = b1[192 + l];
    }
    asm volatile("" ::: "memory");  // loads above cannot remat past this point

    float4 c1 = make_float4(0.f, 0.f, 0.f, 0.f);  // tid<128: L1 cell state (4 units)
    float4 c2 = make_float4(0.f, 0.f, 0.f, 0.f);  // tid 128..191: L2 cell state

    { float* p = (float*)h1_sh; p[tid] = 0.f; p[NT + tid] = 0.f; }
    { float* p = (float*)h2_sh; p[tid] = 0.f; }

    // stage x(0)
    if (tid >= 192) {
        const int i = tid - 192, row = i >> 3, fi = i & 7;
        const float4* xg = (const float4*)(x + (size_t)(r0 + row) * (T_STEPS * 32));
        x_sh[0][row][fi] = xg[fi];
    }
    __syncthreads();

    auto do_z2 = [&](int cA, int cB) {
        #pragma unroll 2
        for (int r = 0; r < RROWS; ++r) {
            float a0 = bias.x, a1 = bias.y;
            #pragma unroll
            for (int j = 0; j < 16; ++j) {
                const float4 hv = h1_sh[r][j];
                FMA4(a0, hv, 4 * j);
                FMA4(a1, hv, 96 + 4 * j);
            }
            #pragma unroll
            for (int j = 0; j < 8; ++j) {
                const float4 hv = h2_sh[r][j];
                FMA4(a0, hv, 64 + 4 * j);
                FMA4(a1, hv, 160 + 4 * j);
            }
            z2s[r][cA] = a0; z2s[r][cB] = a1;
        }
    };

    for (int t = 0; t < T_STEPS; ++t) {
        const int buf = t & 1;

        // early global prefetch of next x slice (wave 3 by tid, any role)
        float4 xnext;
        if (tid >= 192) {
            const int i = tid - 192, row = i >> 3, fi = i & 7;
            const int tn = (t + 1 < T_STEPS) ? t + 1 : T_STEPS - 1;
            const float4* xg = (const float4*)(x + ((size_t)(r0 + row) * T_STEPS + tn) * 32);
            xnext = xg[fi];
        }

        // ---------------- phase A: matmuls ----------------
        if (role <= 1) {
            const int cA = (role == 0) ? l : (64 + l);
            const int cB = cA + 128;
            #pragma unroll 2
            for (int r = 0; r < RROWS; ++r) {
                float a0 = 0.f, a1 = 0.f;
                #pragma unroll
                for (int j = 0; j < 16; ++j) {
                    const float4 hv = h1_sh[r][j];
                    FMA4(a0, hv, 4 * j);
                    FMA4(a1, hv, 64 + 4 * j);
                }
                zp1h[r][cA] = a0; zp1h[r][cB] = a1;
            }
        } else if (role == 2) {
            if (t > 0) do_z2(l, 64 + l);   // z2(t-1): uses h1(t-1), h2(t-2)
        } else {
            #pragma unroll 2
            for (int r = 0; r < RROWS; ++r) {
                float a0 = bias.x, a1 = bias.y, a2 = bias.z, a3 = bias.w;
                #pragma unroll
                for (int j = 0; j < 8; ++j) {
                    const float4 xv = x_sh[buf][r][j];
                    FMA4(a0, xv, 4 * j);
                    FMA4(a1, xv, 32 + 4 * j);
                    FMA4(a2, xv, 64 + 4 * j);
                    FMA4(a3, xv, 96 + 4 * j);
                }
                zp1x[r][l]       = a0;
                zp1x[r][64 + l]  = a1;
                zp1x[r][128 + l] = a2;
                zp1x[r][192 + l] = a3;
            }
        }
        __syncthreads();

        // ---------------- phase B: gates + x stage ----------------
        if (tid < 128) {
            const int r = tid >> 4, q = tid & 15;
            const float4* ph = (const float4*)zp1h[r];
            const float4* px = (const float4*)zp1x[r];
            float4 zi = ph[q],      zf = ph[16 + q], zg = ph[32 + q], zo = ph[48 + q];
            const float4 yi = px[q], yf = px[16 + q], yg = px[32 + q], yo = px[48 + q];
            zi.x += yi.x; zi.y += yi.y; zi.z += yi.z; zi.w += yi.w;
            zf.x += yf.x; zf.y += yf.y; zf.z += yf.z; zf.w += yf.w;
            zg.x += yg.x; zg.y += yg.y; zg.z += yg.z; zg.w += yg.w;
            zo.x += yo.x; zo.y += yo.y; zo.z += yo.z; zo.w += yo.w;
            float4 h;
            GATE1E(x) GATE1E(y) GATE1E(z) GATE1E(w)
            h1_sh[r][q] = h;       // h1(t)
        } else if (tid < 192) {
            if (t > 0) {
                const int i = tid - 128, r = i >> 3, q = i & 7;
                const float4* pz = (const float4*)z2s[r];
                const float4 zi = pz[q], zf = pz[8 + q], zg = pz[16 + q], zo = pz[24 + q];
                float4 h;
                GATE2E(x) GATE2E(y) GATE2E(z) GATE2E(w)
                h2_sh[r][q] = h;   // h2(t-1)
            }
        } else {
            const int i = tid - 192, row = i >> 3, fi = i & 7;
            x_sh[buf ^ 1][row][fi] = xnext;
        }
        __syncthreads();
    }

    // ---------------- epilogue: z2(335) + gate2 ----------------
    if (role == 2) do_z2(l, 64 + l);
    __syncthreads();
    if (tid >= 128 && tid < 192) {
        const int i = tid - 128, r = i >> 3, q = i & 7;
        const float4* pz = (const float4*)z2s[r];
        const float4 zi = pz[q], zf = pz[8 + q], zg = pz[16 + q], zo = pz[24 + q];
        float4 h;
        GATE2E(x) GATE2E(y) GATE2E(z) GATE2E(w)
        h2_sh[r][q] = h;           // h2(335)
    }
    __syncthreads();

    // ---------------- head ----------------
    {
        const float* h2f = (const float*)h2_sh;
        const int r = tid >> 5, cidx = tid & 31;
        float acc = bv[cidx];
        #pragma unroll
        for (int j = 0; j < 32; ++j) acc = fmaf(h2f[r * 32 + j], Wv[j * 32 + cidx], acc);
        t0_sh[r][cidx] = acc;      // v
        __syncthreads();

        float acc2 = bo[cidx];
        #pragma unroll
        for (int j = 0; j < 32; ++j) acc2 = fmaf(t0_sh[r][j], Wo[j * 32 + cidx], acc2);
        __syncthreads();
        t0_sh[r][cidx] = acc2;     // o
        __syncthreads();

        #pragma unroll
        for (int k = 0; k < 2; ++k) {
            const int c64 = cidx + k * 32;
            float a = bd1[c64];
            #pragma unroll
            for (int j = 0; j < 32; ++j) a = fmaf(t0_sh[r][j], Wd1[j * 64 + c64], a);
            d1_sh[r][c64] = fmaxf(a, 0.0f);
        }
        __syncthreads();

        if (tid < RROWS * 24) {
            const int rr = tid / 24, cc = tid - rr * 24;
            float a = bd2[cc];
            #pragma unroll
            for (int j = 0; j < 64; ++j) a = fmaf(d1_sh[rr][j], Wd2[j * 24 + cc], a);
            out[(r0 + rr) * 24 + cc] = a;
        }
    }
}

extern "C" void kernel_launch(void* const* d_in, const int* in_sizes, int n_in,
                              void* d_out, int out_size, void* d_ws, size_t ws_size,
                              hipStream_t stream) {
    const float* x   = (const float*)d_in[0];
    const float* W1  = (const float*)d_in[1];
    const float* U1  = (const float*)d_in[2];
    const float* b1  = (const float*)d_in[3];
    const float* W2  = (const float*)d_in[4];
    const float* U2  = (const float*)d_in[5];
    const float* b2  = (const float*)d_in[6];
    // d_in[7..10] = Wq, bq, Wk, bk — dead (softmax over len-1 axis == 1)
    const float* Wv  = (const float*)d_in[11];
    const float* bv  = (const float*)d_in[12];
    const float* Wo  = (const float*)d_in[13];
    const float* bo  = (const float*)d_in[14];
    const float* Wd1 = (const float*)d_in[15];
    const float* bd1 = (const float*)d_in[16];
    const float* Wd2 = (const float*)d_in[17];
    const float* bd2 = (const float*)d_in[18];
    (void)d_ws; (void)ws_size; (void)in_sizes; (void)n_in; (void)out_size;

    hipLaunchKernelGGL(lstm_fused, dim3(B_TOTAL / RROWS), dim3(NT), 0, stream,
                       x, W1, U1, b1, W2, U2, b2, Wv, bv, Wo, bo,
                       Wd1, bd1, Wd2, bd2, (float*)d_out);
}

// Round 4
// 3885.387 us; speedup vs baseline: 10.9112x; 10.9112x over previous
//
#include <hip/hip_runtime.h>

// PolicyAwareLSTM: 2-layer LSTM (4096 x 336, 32->64->32) + seq1-MHA (two 32x32
// matmuls; Wq/Wk dead: softmax over a length-1 axis == 1) + dense 32->64->24.
// fp32 (no fp32 MFMA on CDNA4) -> VALU + LDS-broadcast design.
//
// Round-3b: same design as R3; fixed macro-parameter capture (`w` param ate the
// `.w` member token). Design to the register allocator (~128 VGPR comfort target
// seen in R1/R2). Per-thread weights capped at 72 floats via split-K (L1: K=96
// split 2, L2: K=96 split 4). 512 threads x 8 rows, 512 blocks, 2 blocks/CU.
// L2 skewed one step behind L1 -> 2 barriers/step. NO asm clobber (R2: forced
// weights to scratch -> 63 GB FETCH, 42 ms).

#define B_TOTAL 4096
#define T_STEPS 336
#define NT      512
#define RROWS   8

__device__ __forceinline__ float fast_sigmoid(float x) {
    return __fdividef(1.0f, 1.0f + __expf(-x));
}
__device__ __forceinline__ float fast_tanh(float x) {
    float ax = fabsf(x);
    float e  = __expf(-2.0f * ax);
    float r  = __fdividef(1.0f - e, 1.0f + e);
    return __builtin_copysignf(r, x);
}

// NOTE: parameter names must not collide with .x/.y/.z/.w member tokens
#define FMA4W(acc, vec, warr, base) \
    acc = fmaf((vec).x, (warr)[(base) + 0], acc); \
    acc = fmaf((vec).y, (warr)[(base) + 1], acc); \
    acc = fmaf((vec).z, (warr)[(base) + 2], acc); \
    acc = fmaf((vec).w, (warr)[(base) + 3], acc);

__global__ __launch_bounds__(NT, 2) void lstm_fused(
    const float* __restrict__ x,
    const float* __restrict__ W1, const float* __restrict__ U1, const float* __restrict__ b1,
    const float* __restrict__ W2, const float* __restrict__ U2, const float* __restrict__ b2,
    const float* __restrict__ Wv, const float* __restrict__ bv,
    const float* __restrict__ Wo, const float* __restrict__ bo,
    const float* __restrict__ Wd1, const float* __restrict__ bd1,
    const float* __restrict__ Wd2, const float* __restrict__ bd2,
    float* __restrict__ out)
{
    __shared__ __align__(16) float4 x_sh[2][RROWS][8];    // x slice, double-buffered
    __shared__ __align__(16) float  hc_sh[RROWS][96];     // [0:64]=h1, [64:96]=h2
    __shared__ __align__(16) float  z1p[2][RROWS][256];   // L1 partials (2 K-halves)
    __shared__ __align__(16) float  z2p[4][RROWS][128];   // L2 partials (4 K-quarters)
    __shared__ float t0_sh[RROWS][32];
    __shared__ float d1_sh[RROWS][64];

    const int tid = threadIdx.x;
    const int r0  = blockIdx.x * RROWS;

    // ---- matmul task mapping (wave-uniform kh/ks, lane-consecutive cols) ----
    const int colA = tid & 255;   // L1 column
    const int kh   = tid >> 8;    // L1 K-half: 0 = x(32)+h1[0:16], 1 = h1[16:64]
    const int colB = tid & 127;   // L2 column
    const int ks   = tid >> 7;    // L2 K-quarter over [h1(64); h2(32)]

    // ---- gate task mapping ----
    const int gr = tid >> 6, gu = tid & 63;          // B-L1: (row, unit)
    const int gr2 = (tid >> 5) & 7, gu2 = tid & 31;  // B-L2 (tid>=256): (row, unit)
    // ---- x staging mapping (wave 7) ----
    const int sr = (tid - 448) >> 3, sq = tid & 7;

    // ---- weights in registers: 48 + 24 = 72 floats (fits under ~128 VGPR) ----
    float wA[48];
    if (kh == 0) {
        #pragma unroll
        for (int k = 0; k < 32; ++k) wA[k] = W1[k * 256 + colA];
        #pragma unroll
        for (int j = 0; j < 16; ++j) wA[32 + j] = U1[j * 256 + colA];
    } else {
        #pragma unroll
        for (int j = 0; j < 48; ++j) wA[j] = U1[(16 + j) * 256 + colA];
    }
    float wB[24];
    #pragma unroll
    for (int j = 0; j < 24; ++j) {
        const int k = 24 * ks + j;
        wB[j] = (k < 64) ? W2[k * 128 + colB] : U2[(k - 64) * 128 + colB];
    }

    // ---- gate biases ----
    const float4 b1v = make_float4(b1[gu], b1[64 + gu], b1[128 + gu], b1[192 + gu]);
    const float4 b2v = make_float4(b2[gu2], b2[32 + gu2], b2[64 + gu2], b2[96 + gu2]);

    float c1 = 0.0f;  // L1 cell state for (gr, gu)
    float c2 = 0.0f;  // L2 cell state for (gr2, gu2), threads >= 256

    // ---- init: zero h1/h2, stage x(0) ----
    if (tid < 256) {
        float* p = (float*)hc_sh;
        p[tid] = 0.0f; p[256 + tid] = 0.0f; p[512 + tid] = 0.0f;
    }
    if (tid >= 448)
        x_sh[0][sr][sq] = ((const float4*)(x + (size_t)(r0 + sr) * (T_STEPS * 32)))[sq];
    __syncthreads();

    for (int t = 0; t < T_STEPS; ++t) {
        const int buf = t & 1;

        float4 xnext;
        if (tid >= 448) {
            const int tn = (t + 1 < T_STEPS) ? t + 1 : T_STEPS - 1;
            xnext = ((const float4*)(x + ((size_t)(r0 + sr) * T_STEPS + tn) * 32))[sq];
        }

        // ================= phase A: matmuls =================
        // A-L1: z1(t) partial (uses x(t), h1(t-1))
        #pragma unroll
        for (int rh = 0; rh < 2; ++rh) {
            float a0 = 0.f, a1 = 0.f, a2 = 0.f, a3 = 0.f;
            if (kh == 0) {
                #pragma unroll
                for (int kv = 0; kv < 8; ++kv) {
                    float4 v0 = x_sh[buf][rh * 4 + 0][kv];
                    float4 v1 = x_sh[buf][rh * 4 + 1][kv];
                    float4 v2 = x_sh[buf][rh * 4 + 2][kv];
                    float4 v3 = x_sh[buf][rh * 4 + 3][kv];
                    FMA4W(a0, v0, wA, 4 * kv) FMA4W(a1, v1, wA, 4 * kv)
                    FMA4W(a2, v2, wA, 4 * kv) FMA4W(a3, v3, wA, 4 * kv)
                }
                #pragma unroll
                for (int kv = 0; kv < 4; ++kv) {
                    float4 v0 = *(const float4*)&hc_sh[rh * 4 + 0][4 * kv];
                    float4 v1 = *(const float4*)&hc_sh[rh * 4 + 1][4 * kv];
                    float4 v2 = *(const float4*)&hc_sh[rh * 4 + 2][4 * kv];
                    float4 v3 = *(const float4*)&hc_sh[rh * 4 + 3][4 * kv];
                    FMA4W(a0, v0, wA, 32 + 4 * kv) FMA4W(a1, v1, wA, 32 + 4 * kv)
                    FMA4W(a2, v2, wA, 32 + 4 * kv) FMA4W(a3, v3, wA, 32 + 4 * kv)
                }
            } else {
                #pragma unroll
                for (int kv = 0; kv < 12; ++kv) {
                    float4 v0 = *(const float4*)&hc_sh[rh * 4 + 0][16 + 4 * kv];
                    float4 v1 = *(const float4*)&hc_sh[rh * 4 + 1][16 + 4 * kv];
                    float4 v2 = *(const float4*)&hc_sh[rh * 4 + 2][16 + 4 * kv];
                    float4 v3 = *(const float4*)&hc_sh[rh * 4 + 3][16 + 4 * kv];
                    FMA4W(a0, v0, wA, 4 * kv) FMA4W(a1, v1, wA, 4 * kv)
                    FMA4W(a2, v2, wA, 4 * kv) FMA4W(a3, v3, wA, 4 * kv)
                }
            }
            z1p[kh][rh * 4 + 0][colA] = a0;
            z1p[kh][rh * 4 + 1][colA] = a1;
            z1p[kh][rh * 4 + 2][colA] = a2;
            z1p[kh][rh * 4 + 3][colA] = a3;
        }

        // A-L2: z2(t-1) partial (uses h1(t-1), h2(t-2) -- both current in hc)
        if (t > 0) {
            #pragma unroll
            for (int rh = 0; rh < 2; ++rh) {
                float a0 = 0.f, a1 = 0.f, a2 = 0.f, a3 = 0.f;
                #pragma unroll
                for (int kv = 0; kv < 6; ++kv) {
                    float4 v0 = *(const float4*)&hc_sh[rh * 4 + 0][24 * ks + 4 * kv];
                    float4 v1 = *(const float4*)&hc_sh[rh * 4 + 1][24 * ks + 4 * kv];
                    float4 v2 = *(const float4*)&hc_sh[rh * 4 + 2][24 * ks + 4 * kv];
                    float4 v3 = *(const float4*)&hc_sh[rh * 4 + 3][24 * ks + 4 * kv];
                    FMA4W(a0, v0, wB, 4 * kv) FMA4W(a1, v1, wB, 4 * kv)
                    FMA4W(a2, v2, wB, 4 * kv) FMA4W(a3, v3, wB, 4 * kv)
                }
                z2p[ks][rh * 4 + 0][colB] = a0;
                z2p[ks][rh * 4 + 1][colB] = a1;
                z2p[ks][rh * 4 + 2][colB] = a2;
                z2p[ks][rh * 4 + 3][colB] = a3;
            }
        }
        __syncthreads();

        // ================= phase B: gates =================
        // B-L1: h1(t) for (gr, gu) -- all 512 threads
        {
            float zi = z1p[0][gr][gu]        + z1p[1][gr][gu]        + b1v.x;
            float zf = z1p[0][gr][64 + gu]   + z1p[1][gr][64 + gu]   + b1v.y;
            float zg = z1p[0][gr][128 + gu]  + z1p[1][gr][128 + gu]  + b1v.z;
            float zo = z1p[0][gr][192 + gu]  + z1p[1][gr][192 + gu]  + b1v.w;
            float ig = fast_sigmoid(zi), fg = fast_sigmoid(zf);
            float gg = fast_tanh(zg),    og = fast_sigmoid(zo);
            c1 = fmaf(fg, c1, ig * gg);
            hc_sh[gr][gu] = og * fast_tanh(c1);
        }
        // B-L2: h2(t-1) for (gr2, gu2) -- threads 256..511
        if (t > 0 && tid >= 256) {
            float zi = z2p[0][gr2][gu2]      + z2p[1][gr2][gu2]      + z2p[2][gr2][gu2]      + z2p[3][gr2][gu2]      + b2v.x;
            float zf = z2p[0][gr2][32 + gu2] + z2p[1][gr2][32 + gu2] + z2p[2][gr2][32 + gu2] + z2p[3][gr2][32 + gu2] + b2v.y;
            float zg = z2p[0][gr2][64 + gu2] + z2p[1][gr2][64 + gu2] + z2p[2][gr2][64 + gu2] + z2p[3][gr2][64 + gu2] + b2v.z;
            float zo = z2p[0][gr2][96 + gu2] + z2p[1][gr2][96 + gu2] + z2p[2][gr2][96 + gu2] + z2p[3][gr2][96 + gu2] + b2v.w;
            float ig = fast_sigmoid(zi), fg = fast_sigmoid(zf);
            float gg = fast_tanh(zg),    og = fast_sigmoid(zo);
            c2 = fmaf(fg, c2, ig * gg);
            hc_sh[gr2][64 + gu2] = og * fast_tanh(c2);
        }
        if (tid >= 448) x_sh[buf ^ 1][sr][sq] = xnext;
        __syncthreads();
    }

    // ================= epilogue: z2(335) + gate2 =================
    {
        #pragma unroll
        for (int rh = 0; rh < 2; ++rh) {
            float a0 = 0.f, a1 = 0.f, a2 = 0.f, a3 = 0.f;
            #pragma unroll
            for (int kv = 0; kv < 6; ++kv) {
                float4 v0 = *(const float4*)&hc_sh[rh * 4 + 0][24 * ks + 4 * kv];
                float4 v1 = *(const float4*)&hc_sh[rh * 4 + 1][24 * ks + 4 * kv];
                float4 v2 = *(const float4*)&hc_sh[rh * 4 + 2][24 * ks + 4 * kv];
                float4 v3 = *(const float4*)&hc_sh[rh * 4 + 3][24 * ks + 4 * kv];
                FMA4W(a0, v0, wB, 4 * kv) FMA4W(a1, v1, wB, 4 * kv)
                FMA4W(a2, v2, wB, 4 * kv) FMA4W(a3, v3, wB, 4 * kv)
            }
            z2p[ks][rh * 4 + 0][colB] = a0;
            z2p[ks][rh * 4 + 1][colB] = a1;
            z2p[ks][rh * 4 + 2][colB] = a2;
            z2p[ks][rh * 4 + 3][colB] = a3;
        }
    }
    __syncthreads();
    if (tid >= 256) {
        float zi = z2p[0][gr2][gu2]      + z2p[1][gr2][gu2]      + z2p[2][gr2][gu2]      + z2p[3][gr2][gu2]      + b2v.x;
        float zf = z2p[0][gr2][32 + gu2] + z2p[1][gr2][32 + gu2] + z2p[2][gr2][32 + gu2] + z2p[3][gr2][32 + gu2] + b2v.y;
        float zg = z2p[0][gr2][64 + gu2] + z2p[1][gr2][64 + gu2] + z2p[2][gr2][64 + gu2] + z2p[3][gr2][64 + gu2] + b2v.z;
        float zo = z2p[0][gr2][96 + gu2] + z2p[1][gr2][96 + gu2] + z2p[2][gr2][96 + gu2] + z2p[3][gr2][96 + gu2] + b2v.w;
        float ig = fast_sigmoid(zi), fg = fast_sigmoid(zf);
        float gg = fast_tanh(zg),    og = fast_sigmoid(zo);
        c2 = fmaf(fg, c2, ig * gg);
        hc_sh[gr2][64 + gu2] = og * fast_tanh(c2);
    }
    __syncthreads();

    // ================= head =================
    const int hr = tid >> 5, hcx = tid & 31;
    if (tid < 256) {
        float acc = bv[hcx];
        #pragma unroll
        for (int j = 0; j < 32; ++j) acc = fmaf(hc_sh[hr][64 + j], Wv[j * 32 + hcx], acc);
        t0_sh[hr][hcx] = acc;                // v
    }
    __syncthreads();
    float acc2 = 0.0f;
    if (tid < 256) {
        acc2 = bo[hcx];
        #pragma unroll
        for (int j = 0; j < 32; ++j) acc2 = fmaf(t0_sh[hr][j], Wo[j * 32 + hcx], acc2);
    }
    __syncthreads();
    if (tid < 256) t0_sh[hr][hcx] = acc2;    // o
    __syncthreads();
    if (tid < 256) {
        #pragma unroll
        for (int k = 0; k < 2; ++k) {
            const int c64 = hcx + k * 32;
            float a = bd1[c64];
            #pragma unroll
            for (int j = 0; j < 32; ++j) a = fmaf(t0_sh[hr][j], Wd1[j * 64 + c64], a);
            d1_sh[hr][c64] = fmaxf(a, 0.0f);
        }
    }
    __syncthreads();
    if (tid < RROWS * 24) {
        const int rr = tid / 24, cc = tid - rr * 24;
        float a = bd2[cc];
        #pragma unroll
        for (int j = 0; j < 64; ++j) a = fmaf(d1_sh[rr][j], Wd2[j * 24 + cc], a);
        out[(r0 + rr) * 24 + cc] = a;
    }
}

extern "C" void kernel_launch(void* const* d_in, const int* in_sizes, int n_in,
                              void* d_out, int out_size, void* d_ws, size_t ws_size,
                              hipStream_t stream) {
    const float* x   = (const float*)d_in[0];
    const float* W1  = (const float*)d_in[1];
    const float* U1  = (const float*)d_in[2];
    const float* b1  = (const float*)d_in[3];
    const float* W2  = (const float*)d_in[4];
    const float* U2  = (const float*)d_in[5];
    const float* b2  = (const float*)d_in[6];
    // d_in[7..10] = Wq, bq, Wk, bk — dead (softmax over len-1 axis == 1)
    const float* Wv  = (const float*)d_in[11];
    const float* bv  = (const float*)d_in[12];
    const float* Wo  = (const float*)d_in[13];
    const float* bo  = (const float*)d_in[14];
    const float* Wd1 = (const float*)d_in[15];
    const float* bd1 = (const float*)d_in[16];
    const float* Wd2 = (const float*)d_in[17];
    const float* bd2 = (const float*)d_in[18];
    (void)d_ws; (void)ws_size; (void)in_sizes; (void)n_in; (void)out_size;

    hipLaunchKernelGGL(lstm_fused, dim3(B_TOTAL / RROWS), dim3(NT), 0, stream,
                       x, W1, U1, b1, W2, U2, b2, Wv, bv, Wo, bo,
                       Wd1, bd1, Wd2, bd2, (float*)d_out);
}